// Round 1
// baseline (133.315 us; speedup 1.0000x reference)
//
#include <hip/hip_runtime.h>

#define T_PAD   962048   // length of reflect-padded waveform
#define T_RAW   960000
#define NFRM    1879
#define OUTW    1876
#define MEDLEN  1864
#define WINL    30
#define PADL    14

// ---------------- Kernel 1: NCCF + per-frame lag selection ----------------
// One wave per frame, 4 frames per 256-thread block.
// Lane t (t<48) owns lags 4t+1 .. 4t+4.
__global__ __launch_bounds__(256) void nccf_kernel(const float* __restrict__ wav,
                                                   int* __restrict__ idxArr) {
    const int bx   = blockIdx.x;     // frame group (4 frames)
    const int b    = blockIdx.y;     // batch
    const int tid  = threadIdx.x;
    const int wave = tid >> 6;
    const int lane = tid & 63;

    __shared__ __align__(16) float sh[2304];
    __shared__ double bsumd[4][44];
    __shared__ double pred[4][45];

    const long a0 = (long)bx * 2048;
    const float* wrow = wav + (long)b * T_RAW;

    // Stage wp[a0 .. a0+2237) with on-the-fly reflect pad + zero tail.
    for (int s = tid; s < 2304; s += 256) {
        float v = 0.0f;
        long t = a0 + s;
        if (s < 2237 && t < T_PAD) {
            long u = t - 1024;
            if (u < 0) u = -u;
            if (u >= T_RAW) u = 2L * (T_RAW - 1) - u;
            v = wrow[u];
        }
        sh[s] = v;
    }
    __syncthreads();

    const int frame = bx * 4 + wave;
    const bool fvalid = (frame < NFRM);
    const float* W = sh + (wave << 9);

    // Per-wave chunk sums of squares (16-element chunks, fp64).
    if (fvalid && lane < 44) {
        const float* p = W + (lane << 4);
        double ssum = 0.0;
        #pragma unroll
        for (int m = 0; m < 16; ++m) { double x = (double)p[m]; ssum = fma(x, x, ssum); }
        bsumd[wave][lane] = ssum;
    }
    __syncthreads();
    if (fvalid && lane == 0) {
        double run = 0.0;
        pred[wave][0] = 0.0;
        for (int i = 0; i < 44; ++i) { run += bsumd[wave][i]; pred[wave][i + 1] = run; }
    }
    __syncthreads();

    // Main NCCF loop: 4 lags per lane, sliding register window, fp64 accum.
    double acc0 = 0.0, acc1 = 0.0, acc2 = 0.0, acc3 = 0.0;
    const int t = lane;
    if (fvalid && t < 48) {
        const float4* W4 = (const float4*)W;
        float4 cur = W4[t];
        double c1 = (double)cur.y, c2 = (double)cur.z, c3 = (double)cur.w;
        for (int k = 0; k < 128; ++k) {
            float4 A  = W4[k];            // wave-uniform broadcast read
            float4 nx = W4[t + k + 1];    // per-lane, 16B stride -> full-rate
            double A0 = (double)A.x,  A1 = (double)A.y,  A2 = (double)A.z,  A3 = (double)A.w;
            double n0 = (double)nx.x, n1 = (double)nx.y, n2 = (double)nx.z, n3 = (double)nx.w;
            acc0 = fma(A0, c1, acc0); acc0 = fma(A1, c2, acc0); acc0 = fma(A2, c3, acc0); acc0 = fma(A3, n0, acc0);
            acc1 = fma(A0, c2, acc1); acc1 = fma(A1, c3, acc1); acc1 = fma(A2, n0, acc1); acc1 = fma(A3, n1, acc1);
            acc2 = fma(A0, c3, acc2); acc2 = fma(A1, n0, acc2); acc2 = fma(A2, n1, acc2); acc2 = fma(A3, n2, acc2);
            acc3 = fma(A0, n0, acc3); acc3 = fma(A1, n1, acc3); acc3 = fma(A2, n2, acc3); acc3 = fma(A3, n3, acc3);
            c1 = n1; c2 = n2; c3 = n3;
        }
    }

    // Per-lane nccf + candidate (max, argmax) pairs; fp64 compares (np-like).
    double bestv = -1e300, halfv = -1e300;
    int bestk = 1 << 30, halfk = 1 << 30;
    if (fvalid && t < 48) {
        double s1 = 1e-9 + sqrt(pred[wave][32]);           // frame norm
        double s1n = s1 * s1;
        double accs[4] = {acc0, acc1, acc2, acc3};
        #pragma unroll
        for (int r = 0; r < 4; ++r) {
            int lag  = 4 * t + 1 + r;
            int kidx = lag - 1;                             // nccf lag index
            if (kidx <= 188) {
                int i16 = lag >> 4;
                double q = pred[wave][i16 + 32] - pred[wave][i16];
                for (int m = (i16 << 4); m < lag; ++m) {
                    double x0 = (double)W[m], x1 = (double)W[m + 512];
                    q += x1 * x1 - x0 * x0;                 // sumsq W[lag .. lag+512)
                }
                double s2 = 1e-9 + sqrt(q);
                double s2n = s2 * s2;
                double v = accs[r] / s1n / s2n;
                if (kidx >= 5) {
                    if (v > bestv || (v == bestv && kidx < bestk)) { bestv = v; bestk = kidx; }
                    if (kidx <= 93 && (v > halfv || (v == halfv && kidx < halfk))) { halfv = v; halfk = kidx; }
                }
            }
        }
    }

    // Wave-wide (max, first-argmax) reduction for both slices.
    #pragma unroll
    for (int off = 32; off >= 1; off >>= 1) {
        double ov = __shfl_xor(bestv, off); int ok = __shfl_xor(bestk, off);
        if (ov > bestv || (ov == bestv && ok < bestk)) { bestv = ov; bestk = ok; }
        double hv = __shfl_xor(halfv, off); int hk = __shfl_xor(halfk, off);
        if (hv > halfv || (hv == halfv && hk < halfk)) { halfv = hv; halfk = hk; }
    }

    if (fvalid && lane == 0) {
        bool m = (halfv > 0.99 * bestv);
        int sel = m ? halfk : bestk;
        idxArr[b * NFRM + frame] = sel + 1;                 // = chosen lag
    }
}

// ---------------- Kernel 2: 30-wide median filter + pitch ----------------
__global__ __launch_bounds__(256) void med_kernel(const int* __restrict__ idxArr,
                                                  float* __restrict__ out) {
    int gid = blockIdx.x * 256 + threadIdx.x;
    if (gid >= 8 * OUTW) return;
    int b = gid / OUTW;
    int i = gid - b * OUTW;
    float o = 0.0f;
    if (i < MEDLEN) {
        const int* row = idxArr + b * NFRM;
        int vals[WINL];
        #pragma unroll
        for (int m = 0; m < WINL; ++m) {
            int s = i + m - PADL;                           // left pad = repeat idx[0]
            vals[m] = row[s < 0 ? 0 : s];
        }
        int med = vals[0];
        #pragma unroll
        for (int c = 0; c < WINL; ++c) {
            int cl = 0, ce = 0;
            #pragma unroll
            for (int m = 0; m < WINL; ++m) {
                cl += (vals[m] <  vals[c]) ? 1 : 0;
                ce += (vals[m] == vals[c]) ? 1 : 0;
            }
            if (cl <= 14 && 14 < cl + ce) med = vals[c];    // rank-14 = sorted[14]
        }
        o = 16000.0f / (1e-9f + (float)med);
    }
    out[gid] = o;
}

extern "C" void kernel_launch(void* const* d_in, const int* in_sizes, int n_in,
                              void* d_out, int out_size, void* d_ws, size_t ws_size,
                              hipStream_t stream) {
    const float* wav = (const float*)d_in[0];
    float* out = (float*)d_out;
    int* idxArr = (int*)d_ws;                               // 8*1879 ints = 60128 B

    dim3 gB((NFRM + 3) / 4, 8);                             // 470 x 8 blocks
    hipLaunchKernelGGL(nccf_kernel, gB, dim3(256), 0, stream, wav, idxArr);

    int total = 8 * OUTW;
    hipLaunchKernelGGL(med_kernel, dim3((total + 255) / 256), dim3(256), 0, stream,
                       idxArr, out);
}

// Round 2
// 101.692 us; speedup vs baseline: 1.3110x; 1.3110x over previous
//
#include <hip/hip_runtime.h>

#define T_PAD   962048   // length of reflect-padded waveform
#define T_RAW   960000
#define NFRM    1879
#define OUTW    1876
#define MEDLEN  1864
#define WINL    30
#define PADL    14

// ---------------- Kernel 1: NCCF + per-frame lag selection ----------------
// One wave per frame, 4 frames per 256-thread block.
// Lane t (t<48) owns lags 4t+1 .. 4t+4.
// Dot products accumulate in fp32 (error ~1e-10 abs on nccf, vs top-2 gaps
// ~1e-5); norms + selection comparisons stay fp64.
__global__ __launch_bounds__(256) void nccf_kernel(const float* __restrict__ wav,
                                                   int* __restrict__ idxArr) {
    const int bx   = blockIdx.x;     // frame group (4 frames)
    const int b    = blockIdx.y;     // batch
    const int tid  = threadIdx.x;
    const int wave = tid >> 6;
    const int lane = tid & 63;

    __shared__ __align__(16) float sh[2304];
    __shared__ double bsumd[4][44];
    __shared__ double pred[4][45];

    const long a0 = (long)bx * 2048;
    const float* wrow = wav + (long)b * T_RAW;

    // Stage wp[a0 .. a0+2237) with on-the-fly reflect pad + zero tail.
    for (int s = tid; s < 2304; s += 256) {
        float v = 0.0f;
        long t = a0 + s;
        if (s < 2237 && t < T_PAD) {
            long u = t - 1024;
            if (u < 0) u = -u;
            if (u >= T_RAW) u = 2L * (T_RAW - 1) - u;
            v = wrow[u];
        }
        sh[s] = v;
    }
    __syncthreads();

    const int frame = bx * 4 + wave;
    const bool fvalid = (frame < NFRM);
    const float* W = sh + (wave << 9);

    // Per-wave chunk sums of squares (16-element chunks, fp64).
    if (fvalid && lane < 44) {
        const float* p = W + (lane << 4);
        double ssum = 0.0;
        #pragma unroll
        for (int m = 0; m < 16; ++m) { double x = (double)p[m]; ssum = fma(x, x, ssum); }
        bsumd[wave][lane] = ssum;
    }
    __syncthreads();
    if (fvalid && lane == 0) {
        double run = 0.0;
        pred[wave][0] = 0.0;
        for (int i = 0; i < 44; ++i) { run += bsumd[wave][i]; pred[wave][i + 1] = run; }
    }
    __syncthreads();

    // Main NCCF loop: 4 lags per lane, sliding register window, fp32 accum.
    float f0 = 0.0f, f1 = 0.0f, f2 = 0.0f, f3 = 0.0f;
    const int t = lane;
    if (fvalid && t < 48) {
        const float4* W4 = (const float4*)W;
        float4 cur = W4[t];
        float c1 = cur.y, c2 = cur.z, c3 = cur.w;
        for (int k = 0; k < 128; ++k) {
            float4 A  = W4[k];            // wave-uniform broadcast read
            float4 nx = W4[t + k + 1];    // per-lane, 16B stride -> full-rate
            f0 = fmaf(A.x, c1,   f0); f0 = fmaf(A.y, c2,   f0); f0 = fmaf(A.z, c3,   f0); f0 = fmaf(A.w, nx.x, f0);
            f1 = fmaf(A.x, c2,   f1); f1 = fmaf(A.y, c3,   f1); f1 = fmaf(A.z, nx.x, f1); f1 = fmaf(A.w, nx.y, f1);
            f2 = fmaf(A.x, c3,   f2); f2 = fmaf(A.y, nx.x, f2); f2 = fmaf(A.z, nx.y, f2); f2 = fmaf(A.w, nx.z, f2);
            f3 = fmaf(A.x, nx.x, f3); f3 = fmaf(A.y, nx.y, f3); f3 = fmaf(A.z, nx.z, f3); f3 = fmaf(A.w, nx.w, f3);
            c1 = nx.y; c2 = nx.z; c3 = nx.w;
        }
    }

    // Per-lane nccf + candidate (max, argmax) pairs; fp64 compares (np-like).
    double bestv = -1e300, halfv = -1e300;
    int bestk = 1 << 30, halfk = 1 << 30;
    if (fvalid && t < 48) {
        double s1 = 1e-9 + sqrt(pred[wave][32]);           // frame norm
        double s1n = s1 * s1;
        double accs[4] = {(double)f0, (double)f1, (double)f2, (double)f3};
        #pragma unroll
        for (int r = 0; r < 4; ++r) {
            int lag  = 4 * t + 1 + r;
            int kidx = lag - 1;                             // nccf lag index
            if (kidx <= 188) {
                int i16 = lag >> 4;
                double q = pred[wave][i16 + 32] - pred[wave][i16];
                for (int m = (i16 << 4); m < lag; ++m) {
                    double x0 = (double)W[m], x1 = (double)W[m + 512];
                    q += x1 * x1 - x0 * x0;                 // sumsq W[lag .. lag+512)
                }
                double s2 = 1e-9 + sqrt(q);
                double s2n = s2 * s2;
                double v = accs[r] / s1n / s2n;
                if (kidx >= 5) {
                    if (v > bestv || (v == bestv && kidx < bestk)) { bestv = v; bestk = kidx; }
                    if (kidx <= 93 && (v > halfv || (v == halfv && kidx < halfk))) { halfv = v; halfk = kidx; }
                }
            }
        }
    }

    // Wave-wide (max, first-argmax) reduction for both slices.
    #pragma unroll
    for (int off = 32; off >= 1; off >>= 1) {
        double ov = __shfl_xor(bestv, off); int ok = __shfl_xor(bestk, off);
        if (ov > bestv || (ov == bestv && ok < bestk)) { bestv = ov; bestk = ok; }
        double hv = __shfl_xor(halfv, off); int hk = __shfl_xor(halfk, off);
        if (hv > halfv || (hv == halfv && hk < halfk)) { halfv = hv; halfk = hk; }
    }

    if (fvalid && lane == 0) {
        bool m = (halfv > 0.99 * bestv);
        int sel = m ? halfk : bestk;
        idxArr[b * NFRM + frame] = sel + 1;                 // = chosen lag
    }
}

// ---------------- Kernel 2: 30-wide median filter + pitch ----------------
__global__ __launch_bounds__(256) void med_kernel(const int* __restrict__ idxArr,
                                                  float* __restrict__ out) {
    int gid = blockIdx.x * 256 + threadIdx.x;
    if (gid >= 8 * OUTW) return;
    int b = gid / OUTW;
    int i = gid - b * OUTW;
    float o = 0.0f;
    if (i < MEDLEN) {
        const int* row = idxArr + b * NFRM;
        int vals[WINL];
        #pragma unroll
        for (int m = 0; m < WINL; ++m) {
            int s = i + m - PADL;                           // left pad = repeat idx[0]
            vals[m] = row[s < 0 ? 0 : s];
        }
        int med = vals[0];
        #pragma unroll
        for (int c = 0; c < WINL; ++c) {
            int cl = 0, ce = 0;
            #pragma unroll
            for (int m = 0; m < WINL; ++m) {
                cl += (vals[m] <  vals[c]) ? 1 : 0;
                ce += (vals[m] == vals[c]) ? 1 : 0;
            }
            if (cl <= 14 && 14 < cl + ce) med = vals[c];    // rank-14 = sorted[14]
        }
        o = 16000.0f / (1e-9f + (float)med);
    }
    out[gid] = o;
}

extern "C" void kernel_launch(void* const* d_in, const int* in_sizes, int n_in,
                              void* d_out, int out_size, void* d_ws, size_t ws_size,
                              hipStream_t stream) {
    const float* wav = (const float*)d_in[0];
    float* out = (float*)d_out;
    int* idxArr = (int*)d_ws;                               // 8*1879 ints = 60128 B

    dim3 gB((NFRM + 3) / 4, 8);                             // 470 x 8 blocks
    hipLaunchKernelGGL(nccf_kernel, gB, dim3(256), 0, stream, wav, idxArr);

    int total = 8 * OUTW;
    hipLaunchKernelGGL(med_kernel, dim3((total + 255) / 256), dim3(256), 0, stream,
                       idxArr, out);
}

// Round 3
// 89.440 us; speedup vs baseline: 1.4905x; 1.1370x over previous
//
#include <hip/hip_runtime.h>

#define T_PAD   962048   // length of reflect-padded waveform
#define T_RAW   960000
#define NFRM    1879
#define OUTW    1876
#define MEDLEN  1864
#define WINL    30
#define PADL    14

// ---------------- Kernel 1: NCCF + per-frame lag selection ----------------
// One wave per frame, 4 frames per 256-thread block.
// Lane t (t<48) owns lags 4t+1 .. 4t+4.
// fp32 inner dot products; fp64 prefix-of-squares for all norms; fp64 compares.
__global__ __launch_bounds__(256) void nccf_kernel(const float* __restrict__ wav,
                                                   int* __restrict__ idxArr) {
    const int bx   = blockIdx.x;     // frame group (4 frames)
    const int b    = blockIdx.y;     // batch
    const int tid  = threadIdx.x;
    const int wave = tid >> 6;
    const int lane = tid & 63;

    __shared__ __align__(16) float sh[2304];
    __shared__ double P[4][705];     // per-frame prefix sum of squares

    const long a0 = (long)bx * 2048;
    const float* wrow = wav + (long)b * T_RAW;

    // Stage wp[a0 .. a0+2237) with on-the-fly reflect pad + zero tail.
    for (int s = tid; s < 2304; s += 256) {
        float v = 0.0f;
        long t = a0 + s;
        if (s < 2237 && t < T_PAD) {
            long u = t - 1024;
            if (u < 0) u = -u;
            if (u >= T_RAW) u = 2L * (T_RAW - 1) - u;
            v = wrow[u];
        }
        sh[s] = v;
    }
    __syncthreads();

    const int frame = bx * 4 + wave;
    const bool fvalid = (frame < NFRM);
    const float* W = sh + (wave << 9);

    // Wave-parallel fp64 prefix-of-squares over W[0..704): 11 elems/lane + scan.
    {
        const float* p = W + lane * 11;
        double part[11];
        double run = 0.0;
        #pragma unroll
        for (int m = 0; m < 11; ++m) { double x = (double)p[m]; run = fma(x, x, run); part[m] = run; }
        double inc = run;
        #pragma unroll
        for (int off = 1; off < 64; off <<= 1) {
            double v = __shfl_up(inc, off);
            if (lane >= off) inc += v;
        }
        double base = inc - run;          // exclusive prefix
        if (lane == 0) P[wave][0] = 0.0;
        #pragma unroll
        for (int m = 0; m < 11; ++m) P[wave][lane * 11 + m + 1] = base + part[m];
    }

    // Main NCCF loop: 4 lags per lane, sliding register window, fp32 accum.
    float f0 = 0.0f, f1 = 0.0f, f2 = 0.0f, f3 = 0.0f;
    const int t = lane;
    if (fvalid && t < 48) {
        const float4* W4 = (const float4*)W;
        float4 cur = W4[t];
        float c1 = cur.y, c2 = cur.z, c3 = cur.w;
        #pragma unroll 4
        for (int k = 0; k < 128; ++k) {
            float4 A  = W4[k];            // wave-uniform broadcast read
            float4 nx = W4[t + k + 1];    // per-lane, 16B stride -> full-rate
            f0 = fmaf(A.x, c1,   f0); f0 = fmaf(A.y, c2,   f0); f0 = fmaf(A.z, c3,   f0); f0 = fmaf(A.w, nx.x, f0);
            f1 = fmaf(A.x, c2,   f1); f1 = fmaf(A.y, c3,   f1); f1 = fmaf(A.z, nx.x, f1); f1 = fmaf(A.w, nx.y, f1);
            f2 = fmaf(A.x, c3,   f2); f2 = fmaf(A.y, nx.x, f2); f2 = fmaf(A.z, nx.y, f2); f2 = fmaf(A.w, nx.z, f2);
            f3 = fmaf(A.x, nx.x, f3); f3 = fmaf(A.y, nx.y, f3); f3 = fmaf(A.z, nx.z, f3); f3 = fmaf(A.w, nx.w, f3);
            c1 = nx.y; c2 = nx.z; c3 = nx.w;
        }
    }

    // Per-lane nccf + candidate (max, argmax) pairs; fp64 compares (np-like).
    double bestv = -1e300, halfv = -1e300;
    int bestk = 1 << 30, halfk = 1 << 30;
    if (fvalid && t < 48) {
        double s1 = 1e-9 + sqrt(P[wave][512]);             // frame norm
        double s1n = s1 * s1;
        double accs[4] = {(double)f0, (double)f1, (double)f2, (double)f3};
        #pragma unroll
        for (int r = 0; r < 4; ++r) {
            int lag  = 4 * t + 1 + r;
            int kidx = lag - 1;                             // nccf lag index
            if (kidx <= 188) {
                double q = P[wave][lag + 512] - P[wave][lag];   // seg sumsq
                double s2 = 1e-9 + sqrt(q);
                double s2n = s2 * s2;
                double v = accs[r] / s1n / s2n;
                if (kidx >= 5) {
                    if (v > bestv || (v == bestv && kidx < bestk)) { bestv = v; bestk = kidx; }
                    if (kidx <= 93 && (v > halfv || (v == halfv && kidx < halfk))) { halfv = v; halfk = kidx; }
                }
            }
        }
    }

    // Wave-wide (max, first-argmax) reduction for both slices.
    #pragma unroll
    for (int off = 32; off >= 1; off >>= 1) {
        double ov = __shfl_xor(bestv, off); int ok = __shfl_xor(bestk, off);
        if (ov > bestv || (ov == bestv && ok < bestk)) { bestv = ov; bestk = ok; }
        double hv = __shfl_xor(halfv, off); int hk = __shfl_xor(halfk, off);
        if (hv > halfv || (hv == halfv && hk < halfk)) { halfv = hv; halfk = hk; }
    }

    if (fvalid && lane == 0) {
        bool m = (halfv > 0.99 * bestv);
        int sel = m ? halfk : bestk;
        idxArr[b * NFRM + frame] = sel + 1;                 // = chosen lag
    }
}

// ---------------- Kernel 2: 30-wide median filter + pitch ----------------
__global__ __launch_bounds__(256) void med_kernel(const int* __restrict__ idxArr,
                                                  float* __restrict__ out) {
    int gid = blockIdx.x * 256 + threadIdx.x;
    if (gid >= 8 * OUTW) return;
    int b = gid / OUTW;
    int i = gid - b * OUTW;
    float o = 0.0f;
    if (i < MEDLEN) {
        const int* row = idxArr + b * NFRM;
        int vals[WINL];
        #pragma unroll
        for (int m = 0; m < WINL; ++m) {
            int s = i + m - PADL;                           // left pad = repeat idx[0]
            vals[m] = row[s < 0 ? 0 : s];
        }
        int med = vals[0];
        #pragma unroll
        for (int c = 0; c < WINL; ++c) {
            int cl = 0, ce = 0;
            #pragma unroll
            for (int m = 0; m < WINL; ++m) {
                cl += (vals[m] <  vals[c]) ? 1 : 0;
                ce += (vals[m] == vals[c]) ? 1 : 0;
            }
            if (cl <= 14 && 14 < cl + ce) med = vals[c];    // rank-14 = sorted[14]
        }
        o = 16000.0f / (1e-9f + (float)med);
    }
    out[gid] = o;
}

extern "C" void kernel_launch(void* const* d_in, const int* in_sizes, int n_in,
                              void* d_out, int out_size, void* d_ws, size_t ws_size,
                              hipStream_t stream) {
    const float* wav = (const float*)d_in[0];
    float* out = (float*)d_out;
    int* idxArr = (int*)d_ws;                               // 8*1879 ints = 60128 B

    dim3 gB((NFRM + 3) / 4, 8);                             // 470 x 8 blocks
    hipLaunchKernelGGL(nccf_kernel, gB, dim3(256), 0, stream, wav, idxArr);

    int total = 8 * OUTW;
    hipLaunchKernelGGL(med_kernel, dim3((total + 255) / 256), dim3(256), 0, stream,
                       idxArr, out);
}